// Round 17
// baseline (186.273 us; speedup 1.0000x reference)
//
#include <hip/hip_runtime.h>
#include <hip/hip_bf16.h>

typedef __bf16 bf16;
typedef __bf16 bf16x8 __attribute__((ext_vector_type(8)));
typedef __bf16 bf16x4 __attribute__((ext_vector_type(4)));
typedef float f32x4 __attribute__((ext_vector_type(4)));

#define HID 1024
#define SEQL 2048
#define NB 4

#define AS1 __attribute__((address_space(1)))
#define AS3 __attribute__((address_space(3)))

// ---- dispatch 1: u_part (fp32-direct, blocks 0-511) + casts + bqk + cbias + RS zero ----
// u_part: UP[ks] = Wo[ti-tile] . Wv[ks-slice][tj-tile] partials (128x128 tile, K-slice
// 128, nt=4, 4 waves). Reads fp32 Wo/Wv directly (independent of cast outputs): per
// K-step, reg-load fp32 -> cvt bf16 -> ds_write (A linear+XOR-swizzled granules; B
// transposed-on-write with same swizzle), barrier, frag reads + 16 MFMA, barrier.
__global__ __launch_bounds__(256) void cast_all(const float* __restrict__ x,
    const float* __restrict__ Wq, const float* __restrict__ Wk,
    const float* __restrict__ Wv, const float* __restrict__ Wo,
    const float* __restrict__ bq, const float* __restrict__ bk,
    const float* __restrict__ bv, const float* __restrict__ bo,
    bf16* __restrict__ XB, bf16* __restrict__ WQKB,
    float* __restrict__ bqkv, float* __restrict__ cbias,
    float* __restrict__ RS, float* __restrict__ UP) {
  __shared__ bf16 sh[8192];  // u_part: As [0,4096) + Bs [4096,8192), both [128][32] swz
  const int b = blockIdx.x;
  const int t = threadIdx.x;
  if (b < 512) {  // ---- u_part ----
    const int ks = b >> 6, ti = (b >> 3) & 7, tj = b & 7;
    const int lane = t & 63, wid = t >> 6;
    const int wr = (wid >> 1) * 64, wc = (wid & 1) * 64;
    const int frow = lane & 15, l = lane >> 4;
    int offA[4], offB[4];
#pragma unroll
    for (int m = 0; m < 4; ++m) {
      const int r = wr + m * 16 + frow;
      offA[m] = r * 32 + ((l ^ ((r >> 1) & 3)) << 3);
    }
#pragma unroll
    for (int n = 0; n < 4; ++n) {
      const int r = wc + n * 16 + frow;
      offB[n] = 4096 + r * 32 + ((l ^ ((r >> 1) & 3)) << 3);
    }
    f32x4 acc[4][4] = {};
    const int ai = t >> 1, ac0 = (t & 1) * 16;       // A: row, col-half
    const int bk2 = t >> 3, bj0 = (t & 7) * 16;      // B: k-row, j-start
    const float* Arow = Wo + (long)(ti * 128 + ai) * HID + ks * 128;
    const float* Brow = Wv + (long)(ks * 128 + bk2) * HID + tj * 128;
    const int ag0 = ac0 >> 3, asw = (ai >> 1) & 3;
    for (int tt = 0; tt < 4; ++tt) {
      const int kk = tt * 32;
      float4 av[4], bv4[4];
#pragma unroll
      for (int j = 0; j < 4; ++j) av[j] = *reinterpret_cast<const float4*>(Arow + kk + ac0 + j * 4);
#pragma unroll
      for (int j = 0; j < 4; ++j) bv4[j] = *reinterpret_cast<const float4*>(Brow + (long)kk * HID + bj0 + j * 4);
      __syncthreads();  // prior step's frag reads complete before overwrite
      bf16x8 aw0 = { (bf16)av[0].x, (bf16)av[0].y, (bf16)av[0].z, (bf16)av[0].w,
                     (bf16)av[1].x, (bf16)av[1].y, (bf16)av[1].z, (bf16)av[1].w };
      bf16x8 aw1 = { (bf16)av[2].x, (bf16)av[2].y, (bf16)av[2].z, (bf16)av[2].w,
                     (bf16)av[3].x, (bf16)av[3].y, (bf16)av[3].z, (bf16)av[3].w };
      *reinterpret_cast<bf16x8*>(&sh[ai * 32 + ((ag0 ^ asw) << 3)]) = aw0;
      *reinterpret_cast<bf16x8*>(&sh[ai * 32 + (((ag0 + 1) ^ asw) << 3)]) = aw1;
#pragma unroll
      for (int j = 0; j < 16; ++j) {
        const int jj = bj0 + j;
        const float v = (j & 2) ? ((j & 1) ? bv4[j >> 2].w : bv4[j >> 2].z)
                                : ((j & 1) ? bv4[j >> 2].y : bv4[j >> 2].x);
        sh[4096 + jj * 32 + (((bk2 >> 3) ^ ((jj >> 1) & 3)) << 3) + (bk2 & 7)] = (bf16)v;
      }
      __syncthreads();
      bf16x8 af[4], bfr[4];
#pragma unroll
      for (int m = 0; m < 4; ++m) af[m] = *reinterpret_cast<const bf16x8*>(&sh[offA[m]]);
#pragma unroll
      for (int n = 0; n < 4; ++n) bfr[n] = *reinterpret_cast<const bf16x8*>(&sh[offB[n]]);
#pragma unroll
      for (int m = 0; m < 4; ++m)
#pragma unroll
        for (int n = 0; n < 4; ++n)
          acc[m][n] = __builtin_amdgcn_mfma_f32_16x16x32_bf16(af[m], bfr[n], acc[m][n], 0, 0, 0);
    }
    float* up = UP + ((long)ks << 20);
    const int crow = l * 4, ccol = frow;
#pragma unroll
    for (int m = 0; m < 4; ++m)
#pragma unroll
      for (int rr = 0; rr < 4; ++rr) {
        const int rowl = wr + m * 16 + crow + rr;
#pragma unroll
        for (int n = 0; n < 4; ++n)
          up[(long)(ti * 128 + rowl) * HID + tj * 128 + wc + n * 16 + ccol] = acc[m][n][rr];
      }
    return;
  }
  if (b < 10752) {  // ---- casts: x (8192 blocks), Wq/Wk (2048 blocks) ----
    const float* src; bf16* dst; long base;
    if (b < 8704) { src = x; dst = XB; base = (long)(b - 512) * 256; }
    else {
      const int w = (b - 8704) >> 10, r = (b - 8704) & 1023;
      src = (w == 0) ? Wq : Wk;
      dst = WQKB + (long)w * (HID * HID);
      base = (long)r * 256;
    }
    const long i = base + t;
    float4 v = reinterpret_cast<const float4*>(src)[i];
    bf16x4 o = { (bf16)v.x, (bf16)v.y, (bf16)v.z, (bf16)v.w };
    reinterpret_cast<bf16x4*>(dst)[i] = o;
  } else if (b < 10760) {  // bqk concat [2048]
    const int i = (b - 10752) * 256 + t;
    bqkv[i] = (i < HID) ? bq[i] : bk[i - HID];
  } else if (b < 10792) {  // cbias = Wo . bv + bo
    const int r = (b - 10760) * 32 + (t >> 3);
    const int l8 = t & 7;
    float s = 0.f;
    const float* wr2 = Wo + (long)r * HID + l8 * 128;
#pragma unroll
    for (int j = 0; j < 32; ++j) {
      float4 v = *reinterpret_cast<const float4*>(wr2 + j * 4);
      const float* bp = bv + l8 * 128 + j * 4;
      s += v.x * bp[0] + v.y * bp[1] + v.z * bp[2] + v.w * bp[3];
    }
    s += __shfl_xor(s, 1);
    s += __shfl_xor(s, 2);
    s += __shfl_xor(s, 4);
    if (l8 == 0) cbias[r] = s + bo[r];
  } else {  // RS zero [8192]
    RS[(b - 10792) * 256 + t] = 0.0f;
  }
}

// ======== shared pipeline pieces (256x128 tile, BK=32, 512 thr, 3-buf counted vmcnt) ========
#define PIPE_DECLS                                                                        \
  const int lane = t & 63;                                                                \
  const int wid = t >> 6;                                                                 \
  const int wr = (wid >> 1) * 64;                                                         \
  const int wc = (wid & 1) * 64;                                                          \
  const int frow = lane & 15;                                                             \
  const int l = lane >> 4;                                                                \
  const int sr = t >> 2;                                                                  \
  const int scol = (((t & 3) ^ ((t >> 3) & 3)) << 3);                                     \
  int offA[4], offB[4];                                                                   \
  _Pragma("unroll") for (int m = 0; m < 4; ++m) {                                         \
    const int r = wr + m * 16 + frow;                                                     \
    offA[m] = r * 32 + ((l ^ ((r >> 1) & 3)) << 3);                                       \
  }                                                                                       \
  _Pragma("unroll") for (int n = 0; n < 4; ++n) {                                         \
    const int r = wc + n * 16 + frow;                                                     \
    offB[n] = 8192 + r * 32 + ((l ^ ((r >> 1) & 3)) << 3);                                \
  }                                                                                       \
  f32x4 acc[4][4] = {};

#define STAGE(bufi, tile_)                                                                \
  {                                                                                       \
    const int kk = (tile_) << 5;                                                          \
    bf16* lb = &lds[bufi][0];                                                             \
    __builtin_amdgcn_global_load_lds(                                                     \
        (const AS1 void*)(Ab + (long)sr * lda + kk + scol),                               \
        (AS3 void*)(lb + t * 8), 16, 0, 0);                                               \
    __builtin_amdgcn_global_load_lds(                                                     \
        (const AS1 void*)(Ab + (long)(sr + 128) * lda + kk + scol),                       \
        (AS3 void*)(lb + 4096 + t * 8), 16, 0, 0);                                        \
    __builtin_amdgcn_global_load_lds(                                                     \
        (const AS1 void*)(Bb + (long)sr * ldb + kk + scol),                               \
        (AS3 void*)(lb + 8192 + t * 8), 16, 0, 0);                                        \
  }

#define PIPE_LOOP                                                                         \
  STAGE(0, 0);                                                                            \
  STAGE(1, 1);                                                                            \
  asm volatile("s_waitcnt vmcnt(3)" ::: "memory");                                        \
  __builtin_amdgcn_s_barrier();                                                           \
  __builtin_amdgcn_sched_barrier(0);                                                      \
  int rb = 0;                                                                             \
  for (int tt = 0; tt < nt; ++tt) {                                                       \
    const bf16* lb = &lds[rb][0];                                                         \
    bf16x8 af[4], bfr[4];                                                                 \
    _Pragma("unroll") for (int m = 0; m < 4; ++m)                                         \
        af[m] = *reinterpret_cast<const bf16x8*>(lb + offA[m]);                           \
    _Pragma("unroll") for (int n = 0; n < 4; ++n)                                         \
        bfr[n] = *reinterpret_cast<const bf16x8*>(lb + offB[n]);                          \
    int sb = rb + 2; if (sb >= 3) sb -= 3;                                                \
    if (tt + 2 < nt) STAGE(sb, tt + 2);                                                   \
    __builtin_amdgcn_s_setprio(1);                                                        \
    _Pragma("unroll") for (int m = 0; m < 4; ++m)                                         \
      _Pragma("unroll") for (int n = 0; n < 4; ++n)                                       \
          acc[m][n] = __builtin_amdgcn_mfma_f32_16x16x32_bf16(af[m], bfr[n], acc[m][n], 0, 0, 0); \
    __builtin_amdgcn_s_setprio(0);                                                        \
    __builtin_amdgcn_sched_barrier(0);                                                    \
    if (tt + 2 < nt)      { asm volatile("s_waitcnt vmcnt(3)" ::: "memory"); }            \
    else if (tt + 1 < nt) { asm volatile("s_waitcnt vmcnt(0)" ::: "memory"); }            \
    if (tt + 1 < nt) {                                                                    \
      __builtin_amdgcn_s_barrier();                                                       \
      __builtin_amdgcn_sched_barrier(0);                                                  \
    }                                                                                     \
    rb = (rb + 1 == 3) ? 0 : rb + 1;                                                      \
  }

// ---------------- dispatch 2: QK projection + u_reduce, flat 528 blocks ----------------
// Swizzled lg: lg<16 -> u_reduce (UB = bf16(sum_ks UP[ks])); else QK 256x128 tile
// (bj=(lg-16)&15, bi=(lg-16)>>4), bias + 1/32 q-scale. XCD-chunked (528 = 8*66).
__global__ __launch_bounds__(512, 4)
void qk_ured(const bf16* __restrict__ XB, const bf16* __restrict__ WQKB,
             const float* __restrict__ bqkv, bf16* __restrict__ QK,
             const float* __restrict__ UP, bf16* __restrict__ UB) {
  const int lin = blockIdx.x;
  const int lg = (lin & 7) * 66 + (lin >> 3);
  const int t = threadIdx.x;
  if (lg < 16) {  // u_reduce: 16 blocks x 512 thr x 32 float4
    const long base = (long)lg * 16384 + t;
    for (int j = 0; j < 32; ++j) {
      const long idx = base + (long)j * 512;
      float4 s = make_float4(0.f, 0.f, 0.f, 0.f);
#pragma unroll
      for (int ks = 0; ks < 8; ++ks) {
        float4 v = reinterpret_cast<const float4*>(UP)[((long)ks << 18) + idx];
        s.x += v.x; s.y += v.y; s.z += v.z; s.w += v.w;
      }
      bf16x4 o = { (bf16)s.x, (bf16)s.y, (bf16)s.z, (bf16)s.w };
      reinterpret_cast<bf16x4*>(UB)[idx] = o;
    }
    return;
  }
  const int bj = (lg - 16) & 15, bi = (lg - 16) >> 4;
  const bf16* Ab = XB + (long)bi * 256 * HID;
  const bf16* Bb = WQKB + (long)bj * 128 * HID;
  const int lda = HID, ldb = HID;
  const int nt = 32;

  __shared__ bf16 lds[3][12288];
  PIPE_DECLS
  PIPE_LOOP

  const int crow = l * 4;
  const int ccol = frow;
#pragma unroll
  for (int m = 0; m < 4; ++m) {
#pragma unroll
    for (int rr = 0; rr < 4; ++rr) {
      const int rowl = wr + m * 16 + crow + rr;
      const long row = (long)bi * 256 + rowl;
#pragma unroll
      for (int n = 0; n < 4; ++n) {
        const int coll = wc + n * 16 + ccol;
        const int colg = bj * 128 + coll;
        float v = acc[m][n][rr] + bqkv[colg];
        v *= (colg < HID ? 0.03125f : 1.0f);
        QK[row * (2 * HID) + colg] = (bf16)v;
      }
    }
  }
}

// ---------------- dispatch 4: final GEMM out = (P' W2^T)/rs + cbias ----------------
template <typename OutT, bool BIAS, bool KLIM, bool RSDIV, bool SWZ>
__global__ __launch_bounds__(512, 4)
void gemm_nt(const bf16* __restrict__ A, const bf16* __restrict__ B,
             const float* __restrict__ bias, OutT* __restrict__ C,
             const float* __restrict__ rs,
             int K, int lda, int ldb, int N, long sA, long sB, long sC) {
  int bj, bi;
  if (SWZ) {
    const int lin = blockIdx.x + gridDim.x * blockIdx.y;
    const int chunk = (gridDim.x * gridDim.y) >> 3;
    const int lg = (lin & 7) * chunk + (lin >> 3);
    bj = lg % gridDim.x; bi = lg / gridDim.x;
  } else { bj = blockIdx.x; bi = blockIdx.y; }
  const int bz = blockIdx.z;
  const int t = threadIdx.x;
  const bf16* Ab = A + (long)bz * sA + (long)bi * 256 * lda;
  const bf16* Bb = B + (long)bz * sB + (long)bj * 128 * ldb;
  const int Kend = KLIM ? ((bi + 1) * 256) : K;
  const int nt = Kend >> 5;

  __shared__ bf16 lds[3][12288];
  PIPE_DECLS
  PIPE_LOOP

  const int crow = l * 4;
  const int ccol = frow;
#pragma unroll
  for (int m = 0; m < 4; ++m) {
#pragma unroll
    for (int rr = 0; rr < 4; ++rr) {
      const int rowl = wr + m * 16 + crow + rr;
      const long row = (long)bi * 256 + rowl;
      const float rsv = RSDIV ? (1.0f / rs[(long)bz * SEQL + row]) : 1.0f;
#pragma unroll
      for (int n = 0; n < 4; ++n) {
        const int coll = wc + n * 16 + ccol;
        const int colg = bj * 128 + coll;
        float v = acc[m][n][rr];
        if (RSDIV) v *= rsv;
        if (BIAS)  v += bias[colg];
        C[(long)bz * sC + row * N + colg] = (OutT)v;
      }
    }
  }
}

// ---------------- dispatch 3: scores + W2, grid (17,8,4), XCD-chunked ----------------
// Live blocks (bj <= 2bi+1): P' = exp(q.k^T) causal (max-free), bf16, + atomic row sums.
// Dead blocks (256 = exactly W2's tiles): W2 = U @ X^T (U = Wo.Wv) — replaces the whole
// V path: out = (P' W2^T)/rs + (Wo.bv + bo).
__global__ __launch_bounds__(512, 4)
void scores_w2(const bf16* __restrict__ QK, const bf16* __restrict__ U,
               const bf16* __restrict__ X,
               bf16* __restrict__ P, bf16* __restrict__ W2, float* __restrict__ rs) {
  const int lin = blockIdx.x + 17 * blockIdx.y + 136 * blockIdx.z;  // grid (17,8,4)
  const int lg = (lin & 7) * 68 + (lin >> 3);
  const int bz = lg / 136;
  const int rem = lg % 136;
  const int bi = rem / 17, bj = rem % 17;
  const int t = threadIdx.x;
  const bool live = (bj <= 2 * bi + 1);
  const bf16 *Ab, *Bb;
  bf16* Cb;
  int lda, ldb;
  if (live) {
    Ab = QK + ((long)bz * SEQL + (long)bi * 256) * (2 * HID);
    Bb = QK + HID + ((long)bz * SEQL + (long)bj * 128) * (2 * HID);
    Cb = P + ((long)bz * SEQL + (long)bi * 256) * SEQL + bj * 128;
    lda = 2 * HID; ldb = 2 * HID;
  } else {
    const int rank = bz * 64 + (15 * bi - bi * (bi - 1)) + (bj - (2 * bi + 2));  // 0..255
    const int wz = rank >> 6, r = rank & 63, mi = r >> 4, nj = r & 15;
    Ab = U + (long)mi * 256 * HID;
    Bb = X + ((long)wz * SEQL + (long)nj * 128) * HID;
    Cb = W2 + ((long)wz * HID + (long)mi * 256) * SEQL + nj * 128;
    lda = HID; ldb = HID;
  }
  const int nt = 32;  // K = 1024

  __shared__ bf16 lds[3][12288];
  PIPE_DECLS
  PIPE_LOOP

  const int crow = l * 4;
  const int ccol = frow;
#pragma unroll
  for (int m = 0; m < 4; ++m) {
#pragma unroll
    for (int rr = 0; rr < 4; ++rr) {
      const int rowl = wr + m * 16 + crow + rr;
      float part = 0.0f;
#pragma unroll
      for (int n = 0; n < 4; ++n) {
        const int coll = wc + n * 16 + ccol;
        float v = acc[m][n][rr];
        if (live) {
          const int row = bi * 256 + rowl;
          const int col = bj * 128 + coll;
          v = (col <= row) ? __expf(v) : 0.0f;  // causal mask + max-free exp
          part += v;
        }
        Cb[(long)rowl * SEQL + coll] = (bf16)v;
      }
      if (live) {
        part += __shfl_xor(part, 1);
        part += __shfl_xor(part, 2);
        part += __shfl_xor(part, 4);
        part += __shfl_xor(part, 8);
        if (frow == 0) atomicAdd(&rs[(long)bz * SEQL + bi * 256 + rowl], part);
      }
    }
  }
}

extern "C" void kernel_launch(void* const* d_in, const int* in_sizes, int n_in,
                              void* d_out, int out_size, void* d_ws, size_t ws_size,
                              hipStream_t stream) {
  const float* x  = (const float*)d_in[0];
  const float* Wq = (const float*)d_in[1];
  const float* bq = (const float*)d_in[2];
  const float* Wk = (const float*)d_in[3];
  const float* bk = (const float*)d_in[4];
  const float* Wv = (const float*)d_in[5];
  const float* bv = (const float*)d_in[6];
  const float* Wo = (const float*)d_in[7];
  const float* bo = (const float*)d_in[8];
  float* out = (float*)d_out;

  // workspace (~136.4 MiB):
  //  [0      ,16.78M)  XB bf16 [8192][1024]
  //  [16.78M ,20.97M)  WQKB (Wq,Wk) bf16
  //  [20.97M ,+8KB)    bqkv ; [+8KB,+12KB) cbias
  //  [22.02M ,24.12M)  UB bf16 [1024][1024]
  //  [33.55M ,67.11M)  QK bf16 [8192][2048]
  //  [83.89M ,100.66M) W2 bf16 [4][1024][2048]
  //  [102.76M,136.31M) P' bf16 [8192][2048] — UPART f32 [8][1024][1024] aliases this
  //                    (written d1, read d2, overwritten by P in d3)
  //  [136.31M,+32KB)   RS
  char* ws = (char*)d_ws;
  bf16*  XB    = (bf16*)(ws);
  bf16*  WQKB  = (bf16*)(ws + 16777216L);
  float* bqkv  = (float*)(ws + 20971520L);
  float* cbias = (float*)(ws + 20979712L);
  bf16*  UB    = (bf16*)(ws + 22020096L);
  bf16*  QK    = (bf16*)(ws + 33554432L);
  bf16*  W2    = (bf16*)(ws + 83886080L);
  bf16*  P     = (bf16*)(ws + 102760448L);
  float* UPART = (float*)(ws + 102760448L);
  float* RS    = (float*)(ws + 136314880L);

  // 1) u_part (fp32-direct) + casts + bqk + cbias + RS zero
  cast_all<<<10824, 256, 0, stream>>>(x, Wq, Wk, Wv, Wo, bq, bk, bv, bo,
                                      XB, WQKB, bqkv, cbias, RS, UPART);

  // 2) QK projection (512 blocks) + u_reduce (16 blocks), XCD-chunked flat grid
  qk_ured<<<528, 512, 0, stream>>>(XB, WQKB, bqkv, QK, UPART, UB);

  // 3) P' = exp(q.k^T) causal + atomic row sums; dead causal slots compute W2 = U X^T
  scores_w2<<<dim3(17, 8, NB), 512, 0, stream>>>(QK, UB, XB, P, W2, RS);

  // 4) out = (P' @ W2^T)/rowsum + (Wo.bv + bo)   (causal K-limit; XCD-swizzled)
  gemm_nt<float, true, true, true, true><<<dim3(8, 8, NB), 512, 0, stream>>>(
      P, W2, cbias, out, RS, SEQL, SEQL, SEQL, HID,
      (long)SEQL * SEQL, (long)HID * SEQL, (long)SEQL * HID);
}

// Round 18
// 166.774 us; speedup vs baseline: 1.1169x; 1.1169x over previous
//
#include <hip/hip_runtime.h>
#include <hip/hip_bf16.h>

typedef __bf16 bf16;
typedef __bf16 bf16x8 __attribute__((ext_vector_type(8)));
typedef __bf16 bf16x4 __attribute__((ext_vector_type(4)));
typedef float f32x4 __attribute__((ext_vector_type(4)));

#define HID 1024
#define SEQL 2048
#define NB 4

#define AS1 __attribute__((address_space(1)))
#define AS3 __attribute__((address_space(3)))

// ---- fused prep: casts (x, W*) + bias concat + RS zero ----
__global__ __launch_bounds__(256) void cast_all(const float* __restrict__ x,
    const float* __restrict__ Wq, const float* __restrict__ Wk,
    const float* __restrict__ Wv, const float* __restrict__ Wo,
    const float* __restrict__ bq, const float* __restrict__ bk, const float* __restrict__ bv,
    bf16* __restrict__ XB, bf16* __restrict__ WQKVB, bf16* __restrict__ WOB,
    float* __restrict__ bqkv, float* __restrict__ RS) {
  const int b = blockIdx.x;
  if (b >= 12300) {  // 32 blocks: zero RS[8192] (atomic rowsum target)
    RS[(b - 12300) * 256 + threadIdx.x] = 0.0f;
    return;
  }
  if (b >= 12288) {  // 12 blocks: concat q/k/v biases [3072]
    const int i = (b - 12288) * 256 + threadIdx.x;
    bqkv[i] = (i < HID) ? bq[i] : (i < 2 * HID ? bk[i - HID] : bv[i - 2 * HID]);
    return;
  }
  const float* src; bf16* dst; long base;
  if (b < 8192) { src = x; dst = XB; base = (long)b * 256; }
  else {
    const int w = (b - 8192) >> 10, r = (b - 8192) & 1023;
    src = (w == 0) ? Wq : (w == 1) ? Wk : (w == 2) ? Wv : Wo;
    dst = (w == 3) ? WOB : WQKVB + (long)w * (HID * HID);
    base = (long)r * 256;
  }
  const long i = base + threadIdx.x;
  float4 v = reinterpret_cast<const float4*>(src)[i];
  bf16x4 o = { (bf16)v.x, (bf16)v.y, (bf16)v.z, (bf16)v.w };
  reinterpret_cast<bf16x4*>(dst)[i] = o;
}

// ======== shared pipeline pieces (256x128 tile, BK=32, 512 thr, 3-buf counted vmcnt) ========
#define PIPE_DECLS                                                                        \
  const int lane = t & 63;                                                                \
  const int wid = t >> 6;                                                                 \
  const int wr = (wid >> 1) * 64;                                                         \
  const int wc = (wid & 1) * 64;                                                          \
  const int frow = lane & 15;                                                             \
  const int l = lane >> 4;                                                                \
  const int sr = t >> 2;                                                                  \
  const int scol = (((t & 3) ^ ((t >> 3) & 3)) << 3);                                     \
  int offA[4], offB[4];                                                                   \
  _Pragma("unroll") for (int m = 0; m < 4; ++m) {                                         \
    const int r = wr + m * 16 + frow;                                                     \
    offA[m] = r * 32 + ((l ^ ((r >> 1) & 3)) << 3);                                       \
  }                                                                                       \
  _Pragma("unroll") for (int n = 0; n < 4; ++n) {                                         \
    const int r = wc + n * 16 + frow;                                                     \
    offB[n] = 8192 + r * 32 + ((l ^ ((r >> 1) & 3)) << 3);                                \
  }                                                                                       \
  f32x4 acc[4][4] = {};

#define STAGE(bufi, tile_)                                                                \
  {                                                                                       \
    const int kk = (tile_) << 5;                                                          \
    bf16* lb = &lds[bufi][0];                                                             \
    __builtin_amdgcn_global_load_lds(                                                     \
        (const AS1 void*)(Ab + (long)sr * lda + kk + scol),                               \
        (AS3 void*)(lb + t * 8), 16, 0, 0);                                               \
    __builtin_amdgcn_global_load_lds(                                                     \
        (const AS1 void*)(Ab + (long)(sr + 128) * lda + kk + scol),                       \
        (AS3 void*)(lb + 4096 + t * 8), 16, 0, 0);                                        \
    __builtin_amdgcn_global_load_lds(                                                     \
        (const AS1 void*)(Bb + (long)sr * ldb + kk + scol),                               \
        (AS3 void*)(lb + 8192 + t * 8), 16, 0, 0);                                        \
  }

#define PIPE_LOOP                                                                         \
  STAGE(0, 0);                                                                            \
  STAGE(1, 1);                                                                            \
  asm volatile("s_waitcnt vmcnt(3)" ::: "memory");                                        \
  __builtin_amdgcn_s_barrier();                                                           \
  __builtin_amdgcn_sched_barrier(0);                                                      \
  int rb = 0;                                                                             \
  for (int tt = 0; tt < nt; ++tt) {                                                       \
    const bf16* lb = &lds[rb][0];                                                         \
    bf16x8 af[4], bfr[4];                                                                 \
    _Pragma("unroll") for (int m = 0; m < 4; ++m)                                         \
        af[m] = *reinterpret_cast<const bf16x8*>(lb + offA[m]);                           \
    _Pragma("unroll") for (int n = 0; n < 4; ++n)                                         \
        bfr[n] = *reinterpret_cast<const bf16x8*>(lb + offB[n]);                          \
    int sb = rb + 2; if (sb >= 3) sb -= 3;                                                \
    if (tt + 2 < nt) STAGE(sb, tt + 2);                                                   \
    __builtin_amdgcn_s_setprio(1);                                                        \
    _Pragma("unroll") for (int m = 0; m < 4; ++m)                                         \
      _Pragma("unroll") for (int n = 0; n < 4; ++n)                                       \
          acc[m][n] = __builtin_amdgcn_mfma_f32_16x16x32_bf16(af[m], bfr[n], acc[m][n], 0, 0, 0); \
    __builtin_amdgcn_s_setprio(0);                                                        \
    __builtin_amdgcn_sched_barrier(0);                                                    \
    if (tt + 2 < nt)      { asm volatile("s_waitcnt vmcnt(3)" ::: "memory"); }            \
    else if (tt + 1 < nt) { asm volatile("s_waitcnt vmcnt(0)" ::: "memory"); }            \
    if (tt + 1 < nt) {                                                                    \
      __builtin_amdgcn_s_barrier();                                                       \
      __builtin_amdgcn_sched_barrier(0);                                                  \
    }                                                                                     \
    rb = (rb + 1 == 3) ? 0 : rb + 1;                                                      \
  }

// ---------------- NT GEMM 256x128 (QKV projection & final P'W2^T) ----------------
// KLIM: causal K-limit (bi+1)*256. RSDIV: v *= 1/rs[bz*SEQL+row] (before bias).
// QKVSC: 1/32 on q columns (after bias).
// SWZMODE: 0=none; 1=chunked XCD swizzle (nwg%8==0); 2=2D XCD chunk for the (24,32)
// QKV grid (each XCD owns an 8bi x 12bj panel set -> smaller per-L2 working set).
template <typename OutT, bool BIAS, bool KLIM, bool RSDIV, bool QKVSC, int SWZMODE>
__global__ __launch_bounds__(512, 4)
void gemm_nt(const bf16* __restrict__ A, const bf16* __restrict__ B,
             const float* __restrict__ bias, OutT* __restrict__ C,
             const float* __restrict__ rs,
             int K, int lda, int ldb, int N, long sA, long sB, long sC) {
  int bj, bi;
  if (SWZMODE == 1) {
    const int lin = blockIdx.x + gridDim.x * blockIdx.y;
    const int chunk = (gridDim.x * gridDim.y) >> 3;
    const int lg = (lin & 7) * chunk + (lin >> 3);
    bj = lg % gridDim.x; bi = lg / gridDim.x;
  } else if (SWZMODE == 2) {  // grid must be (24,32): 8 XCDs x (8 bi x 12 bj)
    const int lin = blockIdx.x + gridDim.x * blockIdx.y;
    const int xcd = lin & 7, idx = lin >> 3;  // idx 0..95
    bi = (xcd >> 1) * 8 + idx / 12;
    bj = (xcd & 1) * 12 + idx % 12;
  } else { bj = blockIdx.x; bi = blockIdx.y; }
  const int bz = blockIdx.z;
  const int t = threadIdx.x;
  const bf16* Ab = A + (long)bz * sA + (long)bi * 256 * lda;
  const bf16* Bb = B + (long)bz * sB + (long)bj * 128 * ldb;
  const int Kend = KLIM ? ((bi + 1) * 256) : K;
  const int nt = Kend >> 5;

  __shared__ bf16 lds[3][12288];
  PIPE_DECLS
  PIPE_LOOP

  const int crow = l * 4;
  const int ccol = frow;
#pragma unroll
  for (int m = 0; m < 4; ++m) {
#pragma unroll
    for (int rr = 0; rr < 4; ++rr) {
      const int rowl = wr + m * 16 + crow + rr;
      const long row = (long)bi * 256 + rowl;
      const float rsv = RSDIV ? (1.0f / rs[(long)bz * SEQL + row]) : 1.0f;
#pragma unroll
      for (int n = 0; n < 4; ++n) {
        const int coll = wc + n * 16 + ccol;
        const int colg = bj * 128 + coll;
        float v = acc[m][n][rr];
        if (RSDIV) v *= rsv;
        if (BIAS)  v += bias[colg];
        if (QKVSC) v *= (colg < HID ? 0.03125f : 1.0f);
        C[(long)bz * sC + row * N + colg] = (OutT)v;
      }
    }
  }
}

// ---------------- scores + W2, one dispatch, grid (17,8,4), XCD-chunked ----------------
// Chunked XCD swizzle: lg = (lin%8)*68 + lin/8 -> each XCD owns a contiguous 68-block
// range (one 4-bi half-batch) so panel re-fetch stays inside one L2.
// Live blocks (bj <= 2bi+1): P' = exp(q.k^T) causal (max-free), bf16, + atomic row sums.
// Dead blocks (256 = exactly W2's tiles): W2 = Wo @ V^T — replaces both the V->VT
// transpose and the output projection (out = (P' W2^T)/rs + bo).
__global__ __launch_bounds__(512, 4)
void scores_w2(const bf16* __restrict__ Q, const bf16* __restrict__ Kp,
               const bf16* __restrict__ Wo, const bf16* __restrict__ V,
               bf16* __restrict__ P, bf16* __restrict__ W2, float* __restrict__ rs) {
  const int lin = blockIdx.x + 17 * blockIdx.y + 136 * blockIdx.z;  // grid (17,8,4)
  const int lg = (lin & 7) * 68 + (lin >> 3);
  const int bz = lg / 136;
  const int rem = lg % 136;
  const int bi = rem / 17, bj = rem % 17;
  const int t = threadIdx.x;
  const bool live = (bj <= 2 * bi + 1);
  const bf16 *Ab, *Bb;
  bf16* Cb;
  int lda, ldb;
  if (live) {
    Ab = Q + ((long)bz * SEQL + (long)bi * 256) * (3 * HID);
    Bb = Kp + ((long)bz * SEQL + (long)bj * 128) * (3 * HID);
    Cb = P + ((long)bz * SEQL + (long)bi * 256) * SEQL + bj * 128;
    lda = 3 * HID; ldb = 3 * HID;
  } else {
    // dense rank over dead slots: per-bi dead = 15-2bi, prefix = 15bi - bi(bi-1)
    const int rank = bz * 64 + (15 * bi - bi * (bi - 1)) + (bj - (2 * bi + 2));  // 0..255
    const int wz = rank >> 6, r = rank & 63, mi = r >> 4, nj = r & 15;
    Ab = Wo + (long)mi * 256 * HID;
    Bb = V + ((long)wz * SEQL + (long)nj * 128) * (3 * HID);
    Cb = W2 + ((long)wz * HID + (long)mi * 256) * SEQL + nj * 128;
    lda = HID; ldb = 3 * HID;
  }
  const int nt = 32;  // K = 1024

  __shared__ bf16 lds[3][12288];
  PIPE_DECLS
  PIPE_LOOP

  const int crow = l * 4;
  const int ccol = frow;
#pragma unroll
  for (int m = 0; m < 4; ++m) {
#pragma unroll
    for (int rr = 0; rr < 4; ++rr) {
      const int rowl = wr + m * 16 + crow + rr;
      float part = 0.0f;
#pragma unroll
      for (int n = 0; n < 4; ++n) {
        const int coll = wc + n * 16 + ccol;
        float v = acc[m][n][rr];
        if (live) {
          const int row = bi * 256 + rowl;
          const int col = bj * 128 + coll;
          v = (col <= row) ? __expf(v) : 0.0f;  // causal mask + max-free exp
          part += v;
        }
        Cb[(long)rowl * SEQL + coll] = (bf16)v;
      }
      if (live) {
        part += __shfl_xor(part, 1);
        part += __shfl_xor(part, 2);
        part += __shfl_xor(part, 4);
        part += __shfl_xor(part, 8);
        if (frow == 0) atomicAdd(&rs[(long)bz * SEQL + bi * 256 + rowl], part);
      }
    }
  }
}

extern "C" void kernel_launch(void* const* d_in, const int* in_sizes, int n_in,
                              void* d_out, int out_size, void* d_ws, size_t ws_size,
                              hipStream_t stream) {
  const float* x  = (const float*)d_in[0];
  const float* Wq = (const float*)d_in[1];
  const float* bq = (const float*)d_in[2];
  const float* Wk = (const float*)d_in[3];
  const float* bk = (const float*)d_in[4];
  const float* Wv = (const float*)d_in[5];
  const float* bv = (const float*)d_in[6];
  const float* Wo = (const float*)d_in[7];
  const float* bo = (const float*)d_in[8];
  float* out = (float*)d_out;

  // workspace (~136.4 MiB), lifetime-safe aliasing (as R13/R14):
  char* ws = (char*)d_ws;
  bf16*  XB    = (bf16*)(ws);
  bf16*  WQKVB = (bf16*)(ws + 16777216L);
  float* bqkv  = (float*)(ws + 23068672L);
  bf16*  QKV   = (bf16*)(ws + 33554432L);
  bf16*  W2    = (bf16*)(ws + 83886080L);
  bf16*  WOB   = (bf16*)(ws + 100663296L);
  bf16*  P     = (bf16*)(ws + 102760448L);
  float* RS    = (float*)(ws + 136314880L);

  // 1) fused casts + bias concat + RS zero
  cast_all<<<12332, 256, 0, stream>>>(x, Wq, Wk, Wv, Wo, bq, bk, bv, XB, WQKVB, WOB, bqkv, RS);

  // 2) QKV projection: [8192,1024] x [3072,1024]^T; q-cols scaled 1/32 (2D XCD chunking)
  gemm_nt<bf16, true, false, false, true, 2><<<dim3(24, 32, 1), 512, 0, stream>>>(
      XB, WQKVB, bqkv, QKV, nullptr, HID, HID, HID, 3 * HID, 0, 0, 0);

  // 3) P' = exp(q.k^T) causal + atomic row sums; dead causal slots compute W2 = Wo V^T
  scores_w2<<<dim3(17, 8, NB), 512, 0, stream>>>(
      QKV, QKV + HID, WOB, QKV + 2 * HID, P, W2, RS);

  // 4) out = (P' @ W2^T)/rowsum + bo   (causal K-limit, 256-granular; XCD-swizzled)
  gemm_nt<float, true, true, true, false, 1><<<dim3(8, 8, NB), 512, 0, stream>>>(
      P, W2, bo, out, RS, SEQL, SEQL, SEQL, HID,
      (long)SEQL * SEQL, (long)HID * SEQL, (long)SEQL * HID);
}

// Round 19
// 164.176 us; speedup vs baseline: 1.1346x; 1.0158x over previous
//
#include <hip/hip_runtime.h>
#include <hip/hip_bf16.h>

typedef __bf16 bf16;
typedef __bf16 bf16x8 __attribute__((ext_vector_type(8)));
typedef __bf16 bf16x4 __attribute__((ext_vector_type(4)));
typedef float f32x4 __attribute__((ext_vector_type(4)));

#define HID 1024
#define SEQL 2048
#define NB 4

#define AS1 __attribute__((address_space(1)))
#define AS3 __attribute__((address_space(3)))

// ---- fused prep: casts (x, W*) + bias concat + RS zero ----
__global__ __launch_bounds__(256) void cast_all(const float* __restrict__ x,
    const float* __restrict__ Wq, const float* __restrict__ Wk,
    const float* __restrict__ Wv, const float* __restrict__ Wo,
    const float* __restrict__ bq, const float* __restrict__ bk, const float* __restrict__ bv,
    bf16* __restrict__ XB, bf16* __restrict__ WQKVB, bf16* __restrict__ WOB,
    float* __restrict__ bqkv, float* __restrict__ RS) {
  const int b = blockIdx.x;
  if (b >= 12300) {  // 32 blocks: zero RS[8192] (atomic rowsum target)
    RS[(b - 12300) * 256 + threadIdx.x] = 0.0f;
    return;
  }
  if (b >= 12288) {  // 12 blocks: concat q/k/v biases [3072]
    const int i = (b - 12288) * 256 + threadIdx.x;
    bqkv[i] = (i < HID) ? bq[i] : (i < 2 * HID ? bk[i - HID] : bv[i - 2 * HID]);
    return;
  }
  const float* src; bf16* dst; long base;
  if (b < 8192) { src = x; dst = XB; base = (long)b * 256; }
  else {
    const int w = (b - 8192) >> 10, r = (b - 8192) & 1023;
    src = (w == 0) ? Wq : (w == 1) ? Wk : (w == 2) ? Wv : Wo;
    dst = (w == 3) ? WOB : WQKVB + (long)w * (HID * HID);
    base = (long)r * 256;
  }
  const long i = base + threadIdx.x;
  float4 v = reinterpret_cast<const float4*>(src)[i];
  bf16x4 o = { (bf16)v.x, (bf16)v.y, (bf16)v.z, (bf16)v.w };
  reinterpret_cast<bf16x4*>(dst)[i] = o;
}

// ======== shared pipeline pieces (256x128 tile, BK=32, 512 thr, 3-buf counted vmcnt) ========
#define PIPE_DECLS                                                                        \
  const int lane = t & 63;                                                                \
  const int wid = t >> 6;                                                                 \
  const int wr = (wid >> 1) * 64;                                                         \
  const int wc = (wid & 1) * 64;                                                          \
  const int frow = lane & 15;                                                             \
  const int l = lane >> 4;                                                                \
  const int sr = t >> 2;                                                                  \
  const int scol = (((t & 3) ^ ((t >> 3) & 3)) << 3);                                     \
  int offA[4], offB[4];                                                                   \
  _Pragma("unroll") for (int m = 0; m < 4; ++m) {                                         \
    const int r = wr + m * 16 + frow;                                                     \
    offA[m] = r * 32 + ((l ^ ((r >> 1) & 3)) << 3);                                       \
  }                                                                                       \
  _Pragma("unroll") for (int n = 0; n < 4; ++n) {                                         \
    const int r = wc + n * 16 + frow;                                                     \
    offB[n] = 8192 + r * 32 + ((l ^ ((r >> 1) & 3)) << 3);                                \
  }                                                                                       \
  f32x4 acc[4][4] = {};

#define STAGE(bufi, tile_)                                                                \
  {                                                                                       \
    const int kk = (tile_) << 5;                                                          \
    bf16* lb = &lds[bufi][0];                                                             \
    __builtin_amdgcn_global_load_lds(                                                     \
        (const AS1 void*)(Ab + (long)sr * lda + kk + scol),                               \
        (AS3 void*)(lb + t * 8), 16, 0, 0);                                               \
    __builtin_amdgcn_global_load_lds(                                                     \
        (const AS1 void*)(Ab + (long)(sr + 128) * lda + kk + scol),                       \
        (AS3 void*)(lb + 4096 + t * 8), 16, 0, 0);                                        \
    __builtin_amdgcn_global_load_lds(                                                     \
        (const AS1 void*)(Bb + (long)sr * ldb + kk + scol),                               \
        (AS3 void*)(lb + 8192 + t * 8), 16, 0, 0);                                        \
  }

#define PIPE_LOOP                                                                         \
  STAGE(0, 0);                                                                            \
  STAGE(1, 1);                                                                            \
  asm volatile("s_waitcnt vmcnt(3)" ::: "memory");                                        \
  __builtin_amdgcn_s_barrier();                                                           \
  __builtin_amdgcn_sched_barrier(0);                                                      \
  int rb = 0;                                                                             \
  for (int tt = 0; tt < nt; ++tt) {                                                       \
    const bf16* lb = &lds[rb][0];                                                         \
    bf16x8 af[4], bfr[4];                                                                 \
    _Pragma("unroll") for (int m = 0; m < 4; ++m)                                         \
        af[m] = *reinterpret_cast<const bf16x8*>(lb + offA[m]);                           \
    _Pragma("unroll") for (int n = 0; n < 4; ++n)                                         \
        bfr[n] = *reinterpret_cast<const bf16x8*>(lb + offB[n]);                          \
    int sb = rb + 2; if (sb >= 3) sb -= 3;                                                \
    if (tt + 2 < nt) STAGE(sb, tt + 2);                                                   \
    __builtin_amdgcn_s_setprio(1);                                                        \
    _Pragma("unroll") for (int m = 0; m < 4; ++m)                                         \
      _Pragma("unroll") for (int n = 0; n < 4; ++n)                                       \
          acc[m][n] = __builtin_amdgcn_mfma_f32_16x16x32_bf16(af[m], bfr[n], acc[m][n], 0, 0, 0); \
    __builtin_amdgcn_s_setprio(0);                                                        \
    __builtin_amdgcn_sched_barrier(0);                                                    \
    if (tt + 2 < nt)      { asm volatile("s_waitcnt vmcnt(3)" ::: "memory"); }            \
    else if (tt + 1 < nt) { asm volatile("s_waitcnt vmcnt(0)" ::: "memory"); }            \
    if (tt + 1 < nt) {                                                                    \
      __builtin_amdgcn_s_barrier();                                                       \
      __builtin_amdgcn_sched_barrier(0);                                                  \
    }                                                                                     \
    rb = (rb + 1 == 3) ? 0 : rb + 1;                                                      \
  }

// ---------------- NT GEMM 256x128 (QKV projection & final P'W2^T) ----------------
// KLIM: causal K-limit (bi+1)*256. RSDIV: v *= 1/rs[bz*SEQL+row] (before bias).
// QKVSC: 1/32 on q columns (after bias).
// SWZMODE: 0=none; 1=chunked XCD swizzle (nwg%8==0); 2=2D XCD chunk for the (24,32)
// QKV grid (each XCD owns an 8bi x 12bj panel set -> smaller per-L2 working set).
template <typename OutT, bool BIAS, bool KLIM, bool RSDIV, bool QKVSC, int SWZMODE>
__global__ __launch_bounds__(512, 4)
void gemm_nt(const bf16* __restrict__ A, const bf16* __restrict__ B,
             const float* __restrict__ bias, OutT* __restrict__ C,
             const float* __restrict__ rs,
             int K, int lda, int ldb, int N, long sA, long sB, long sC) {
  int bj, bi;
  if (SWZMODE == 1) {
    const int lin = blockIdx.x + gridDim.x * blockIdx.y;
    const int chunk = (gridDim.x * gridDim.y) >> 3;
    const int lg = (lin & 7) * chunk + (lin >> 3);
    bj = lg % gridDim.x; bi = lg / gridDim.x;
  } else if (SWZMODE == 2) {  // grid must be (24,32): 8 XCDs x (8 bi x 12 bj)
    const int lin = blockIdx.x + gridDim.x * blockIdx.y;
    const int xcd = lin & 7, idx = lin >> 3;  // idx 0..95
    bi = (xcd >> 1) * 8 + idx / 12;
    bj = (xcd & 1) * 12 + idx % 12;
  } else { bj = blockIdx.x; bi = blockIdx.y; }
  const int bz = blockIdx.z;
  const int t = threadIdx.x;
  const bf16* Ab = A + (long)bz * sA + (long)bi * 256 * lda;
  const bf16* Bb = B + (long)bz * sB + (long)bj * 128 * ldb;
  const int Kend = KLIM ? ((bi + 1) * 256) : K;
  const int nt = Kend >> 5;

  __shared__ bf16 lds[3][12288];
  PIPE_DECLS
  PIPE_LOOP

  const int crow = l * 4;
  const int ccol = frow;
#pragma unroll
  for (int m = 0; m < 4; ++m) {
#pragma unroll
    for (int rr = 0; rr < 4; ++rr) {
      const int rowl = wr + m * 16 + crow + rr;
      const long row = (long)bi * 256 + rowl;
      const float rsv = RSDIV ? (1.0f / rs[(long)bz * SEQL + row]) : 1.0f;
#pragma unroll
      for (int n = 0; n < 4; ++n) {
        const int coll = wc + n * 16 + ccol;
        const int colg = bj * 128 + coll;
        float v = acc[m][n][rr];
        if (RSDIV) v *= rsv;
        if (BIAS)  v += bias[colg];
        if (QKVSC) v *= (colg < HID ? 0.03125f : 1.0f);
        C[(long)bz * sC + row * N + colg] = (OutT)v;
      }
    }
  }
}

// ---------------- scores + W2, one dispatch, grid (17,8,4), XCD-chunked ----------------
// Chunked XCD swizzle: lg = (lin%8)*68 + lin/8 -> each XCD owns a contiguous 68-block
// range (one 4-bi half-batch) so panel re-fetch stays inside one L2.
// Live blocks (bj <= 2bi+1): P' = exp(q.k^T) causal (max-free), bf16, + atomic row sums.
// Dead blocks (256 = exactly W2's tiles): W2 = Wo @ V^T — replaces both the V->VT
// transpose and the output projection (out = (P' W2^T)/rs + bo).
__global__ __launch_bounds__(512, 4)
void scores_w2(const bf16* __restrict__ Q, const bf16* __restrict__ Kp,
               const bf16* __restrict__ Wo, const bf16* __restrict__ V,
               bf16* __restrict__ P, bf16* __restrict__ W2, float* __restrict__ rs) {
  const int lin = blockIdx.x + 17 * blockIdx.y + 136 * blockIdx.z;  // grid (17,8,4)
  const int lg = (lin & 7) * 68 + (lin >> 3);
  const int bz = lg / 136;
  const int rem = lg % 136;
  const int bi = rem / 17, bj = rem % 17;
  const int t = threadIdx.x;
  const bool live = (bj <= 2 * bi + 1);
  const bf16 *Ab, *Bb;
  bf16* Cb;
  int lda, ldb;
  if (live) {
    Ab = Q + ((long)bz * SEQL + (long)bi * 256) * (3 * HID);
    Bb = Kp + ((long)bz * SEQL + (long)bj * 128) * (3 * HID);
    Cb = P + ((long)bz * SEQL + (long)bi * 256) * SEQL + bj * 128;
    lda = 3 * HID; ldb = 3 * HID;
  } else {
    // dense rank over dead slots: per-bi dead = 15-2bi, prefix = 15bi - bi(bi-1)
    const int rank = bz * 64 + (15 * bi - bi * (bi - 1)) + (bj - (2 * bi + 2));  // 0..255
    const int wz = rank >> 6, r = rank & 63, mi = r >> 4, nj = r & 15;
    Ab = Wo + (long)mi * 256 * HID;
    Bb = V + ((long)wz * SEQL + (long)nj * 128) * (3 * HID);
    Cb = W2 + ((long)wz * HID + (long)mi * 256) * SEQL + nj * 128;
    lda = HID; ldb = 3 * HID;
  }
  const int nt = 32;  // K = 1024

  __shared__ bf16 lds[3][12288];
  PIPE_DECLS
  PIPE_LOOP

  const int crow = l * 4;
  const int ccol = frow;
#pragma unroll
  for (int m = 0; m < 4; ++m) {
#pragma unroll
    for (int rr = 0; rr < 4; ++rr) {
      const int rowl = wr + m * 16 + crow + rr;
      float part = 0.0f;
#pragma unroll
      for (int n = 0; n < 4; ++n) {
        const int coll = wc + n * 16 + ccol;
        float v = acc[m][n][rr];
        if (live) {
          const int row = bi * 256 + rowl;
          const int col = bj * 128 + coll;
          v = (col <= row) ? __expf(v) : 0.0f;  // causal mask + max-free exp
          part += v;
        }
        Cb[(long)rowl * SEQL + coll] = (bf16)v;
      }
      if (live) {
        part += __shfl_xor(part, 1);
        part += __shfl_xor(part, 2);
        part += __shfl_xor(part, 4);
        part += __shfl_xor(part, 8);
        if (frow == 0) atomicAdd(&rs[(long)bz * SEQL + bi * 256 + rowl], part);
      }
    }
  }
}

extern "C" void kernel_launch(void* const* d_in, const int* in_sizes, int n_in,
                              void* d_out, int out_size, void* d_ws, size_t ws_size,
                              hipStream_t stream) {
  const float* x  = (const float*)d_in[0];
  const float* Wq = (const float*)d_in[1];
  const float* bq = (const float*)d_in[2];
  const float* Wk = (const float*)d_in[3];
  const float* bk = (const float*)d_in[4];
  const float* Wv = (const float*)d_in[5];
  const float* bv = (const float*)d_in[6];
  const float* Wo = (const float*)d_in[7];
  const float* bo = (const float*)d_in[8];
  float* out = (float*)d_out;

  // workspace (~136.4 MiB), lifetime-safe aliasing (as R13/R14):
  char* ws = (char*)d_ws;
  bf16*  XB    = (bf16*)(ws);
  bf16*  WQKVB = (bf16*)(ws + 16777216L);
  float* bqkv  = (float*)(ws + 23068672L);
  bf16*  QKV   = (bf16*)(ws + 33554432L);
  bf16*  W2    = (bf16*)(ws + 83886080L);
  bf16*  WOB   = (bf16*)(ws + 100663296L);
  bf16*  P     = (bf16*)(ws + 102760448L);
  float* RS    = (float*)(ws + 136314880L);

  // 1) fused casts + bias concat + RS zero
  cast_all<<<12332, 256, 0, stream>>>(x, Wq, Wk, Wv, Wo, bq, bk, bv, XB, WQKVB, WOB, bqkv, RS);

  // 2) QKV projection: [8192,1024] x [3072,1024]^T; q-cols scaled 1/32 (2D XCD chunking)
  gemm_nt<bf16, true, false, false, true, 2><<<dim3(24, 32, 1), 512, 0, stream>>>(
      XB, WQKVB, bqkv, QKV, nullptr, HID, HID, HID, 3 * HID, 0, 0, 0);

  // 3) P' = exp(q.k^T) causal + atomic row sums; dead causal slots compute W2 = Wo V^T
  scores_w2<<<dim3(17, 8, NB), 512, 0, stream>>>(
      QKV, QKV + HID, WOB, QKV + 2 * HID, P, W2, RS);

  // 4) out = (P' @ W2^T)/rowsum + bo   (causal K-limit, 256-granular; no swizzle —
  //    R18 A/B showed swizzle costs ~3us here when P/W2 are L3-resident)
  gemm_nt<float, true, true, true, false, 0><<<dim3(8, 8, NB), 512, 0, stream>>>(
      P, W2, bo, out, RS, SEQL, SEQL, SEQL, HID,
      (long)SEQL * SEQL, (long)HID * SEQL, (long)SEQL * HID);
}